// Round 1
// baseline (63.334 us; speedup 1.0000x reference)
//
#include <hip/hip_runtime.h>
#include <math.h>

#define TWO_PI_F 6.28318530717958647692f

// ---------------------------------------------------------------------------
// Kernel 0: sin/cos table for the 4 periods.
// tbl[t*8 + 2*i] = sin(2*pi*freq_i*tv[t]),  tbl[t*8 + 2*i + 1] = cos(...)
// ---------------------------------------------------------------------------
__global__ void k_table(const float* __restrict__ tv, float* __restrict__ tbl, int T) {
    int t = blockIdx.x * blockDim.x + threadIdx.x;
    if (t >= T) return;
    const float freqs[4] = {4.0f, 2.0f, 1.0f, 0.5f};
    float tvv = tv[t];
#pragma unroll
    for (int i = 0; i < 4; ++i) {
        float s, c;
        sincosf(TWO_PI_F * freqs[i] * tvv, &s, &c);
        tbl[t * 8 + 2 * i]     = s;
        tbl[t * 8 + 2 * i + 1] = c;
    }
}

// ---------------------------------------------------------------------------
// Kernel 1: per-station coefficients.
// For each station n and period i:
//   nbr_avg = sum_k amp[nbr[k],i]*w[k]
//   s_amp   = clip(0.85*amp + 0.15*nbr_avg, bmin[i,n], bmax[i,n])
//   (cr,ci) = (cos ph, sin ph); (ar,ai) = weighted nbr avg of (cr,ci)
//   (mr,mi) = 0.9*(cr,ci) + 0.1*(ar,ai)
//   P = s_amp*mr/|m| (sin coeff), Q = s_amp*mi/|m| (cos coeff)
// pq[n*8 + 2*i] = P_i, pq[n*8 + 2*i + 1] = Q_i
// ---------------------------------------------------------------------------
__global__ void k_coeffs(const float* __restrict__ amp, const float* __restrict__ ph,
                         const float* __restrict__ w, const int* __restrict__ nbr,
                         const float* __restrict__ bmin, const float* __restrict__ bmax,
                         float* __restrict__ pq, int N, int K) {
    int n = blockIdx.x * blockDim.x + threadIdx.x;
    if (n >= N) return;

    float na[4] = {0.f, 0.f, 0.f, 0.f};
    float ar[4] = {0.f, 0.f, 0.f, 0.f};
    float ai[4] = {0.f, 0.f, 0.f, 0.f};

    for (int k = 0; k < K; ++k) {
        float wk = w[(size_t)n * K + k];
        int   m  = nbr[(size_t)n * K + k];
        const float4 am = *(const float4*)(amp + (size_t)m * 4);
        const float4 pm = *(const float4*)(ph + (size_t)m * 4);
        float s, c;
        na[0] += am.x * wk; sincosf(pm.x, &s, &c); ar[0] += c * wk; ai[0] += s * wk;
        na[1] += am.y * wk; sincosf(pm.y, &s, &c); ar[1] += c * wk; ai[1] += s * wk;
        na[2] += am.z * wk; sincosf(pm.z, &s, &c); ar[2] += c * wk; ai[2] += s * wk;
        na[3] += am.w * wk; sincosf(pm.w, &s, &c); ar[3] += c * wk; ai[3] += s * wk;
    }

    const float4 a0 = *(const float4*)(amp + (size_t)n * 4);
    const float4 p0 = *(const float4*)(ph + (size_t)n * 4);
    const float av[4] = {a0.x, a0.y, a0.z, a0.w};
    const float pv[4] = {p0.x, p0.y, p0.z, p0.w};

#pragma unroll
    for (int i = 0; i < 4; ++i) {
        float s_amp = 0.85f * av[i] + 0.15f * na[i];
        float lo = bmin[(size_t)i * N + n];
        float hi = bmax[(size_t)i * N + n];
        s_amp = fminf(fmaxf(s_amp, lo), hi);
        float cr, ci;
        sincosf(pv[i], &ci, &cr);
        float mr = 0.9f * cr + 0.1f * ar[i];
        float mi = 0.9f * ci + 0.1f * ai[i];
        float inv = rsqrtf(mr * mr + mi * mi);  // |m| >= 0.8, safe
        pq[(size_t)n * 8 + 2 * i]     = s_amp * mr * inv;
        pq[(size_t)n * 8 + 2 * i + 1] = s_amp * mi * inv;
    }
}

// ---------------------------------------------------------------------------
// Kernel 2: output sweep. Block = 256 threads; each thread owns one quad of 4
// consecutive t values (table cached in registers) and loops over ROWS rows.
// out[n*T + t] = c[n] + b[n]*tv[t] + sum_i (P_i*sin_i(t) + Q_i*cos_i(t))
// ---------------------------------------------------------------------------
template <int ROWS>
__global__ __launch_bounds__(256) void k_sweep(
        const float* __restrict__ co, const float* __restrict__ lt,
        const float* __restrict__ pq, const float* __restrict__ tbl,
        const float* __restrict__ tv, float* __restrict__ out, int N, int T) {
    const int tid = threadIdx.x;
    const int nq  = (T + 3) >> 2;                      // number of t-quads
    const int qi  = blockIdx.y * 256 + tid;            // this thread's quad
    const int t0  = qi * 4;
    const bool act = (qi < nq);

    float tvq[4];
    float sn[4][4], cs[4][4];   // [q][period]
    if (act) {
#pragma unroll
        for (int q = 0; q < 4; ++q) {
            int t = t0 + q; if (t > T - 1) t = T - 1;
            tvq[q] = tv[t];
            const float4 A = *(const float4*)(tbl + (size_t)t * 8);
            const float4 B = *(const float4*)(tbl + (size_t)t * 8 + 4);
            sn[q][0] = A.x; cs[q][0] = A.y;
            sn[q][1] = A.z; cs[q][1] = A.w;
            sn[q][2] = B.x; cs[q][2] = B.y;
            sn[q][3] = B.z; cs[q][3] = B.w;
        }
    }

    const int nbase = blockIdx.x * ROWS;
#pragma unroll 1
    for (int r = 0; r < ROWS; ++r) {
        const int n = nbase + r;
        if (n >= N) break;
        // Uniform (block-wide) loads -> scalar path
        const float  c0  = co[n];
        const float  b   = lt[n];
        const float4 PQ0 = *(const float4*)(pq + (size_t)n * 8);
        const float4 PQ1 = *(const float4*)(pq + (size_t)n * 8 + 4);
        if (!act) continue;

        float v[4];
#pragma unroll
        for (int q = 0; q < 4; ++q) {
            float x = fmaf(b, tvq[q], c0);
            x = fmaf(PQ0.x, sn[q][0], x);
            x = fmaf(PQ0.y, cs[q][0], x);
            x = fmaf(PQ0.z, sn[q][1], x);
            x = fmaf(PQ0.w, cs[q][1], x);
            x = fmaf(PQ1.x, sn[q][2], x);
            x = fmaf(PQ1.y, cs[q][2], x);
            x = fmaf(PQ1.z, sn[q][3], x);
            x = fmaf(PQ1.w, cs[q][3], x);
            v[q] = x;
        }
        float* dst = out + (size_t)n * T + t0;
        if (t0 + 3 < T) {
            float4 o; o.x = v[0]; o.y = v[1]; o.z = v[2]; o.w = v[3];
            *(float4*)dst = o;
        } else {
#pragma unroll
            for (int q = 0; q < 4; ++q)
                if (t0 + q < T) dst[q] = v[q];
        }
    }
}

extern "C" void kernel_launch(void* const* d_in, const int* in_sizes, int n_in,
                              void* d_out, int out_size, void* d_ws, size_t ws_size,
                              hipStream_t stream) {
    const float* tv   = (const float*)d_in[0];
    const float* co   = (const float*)d_in[1];
    const float* lt   = (const float*)d_in[2];
    const float* amp  = (const float*)d_in[3];
    const float* ph   = (const float*)d_in[4];
    const float* w    = (const float*)d_in[5];
    const float* bmin = (const float*)d_in[6];
    const float* bmax = (const float*)d_in[7];
    const int*   nbr  = (const int*)d_in[8];

    const int T = in_sizes[0];
    const int N = in_sizes[1];
    const int K = in_sizes[5] / N;

    float* pq  = (float*)d_ws;                 // N*8 floats
    float* tbl = pq + (size_t)N * 8;           // T*8 floats

    float* out = (float*)d_out;

    // Kernel 0: table
    k_table<<<(T + 255) / 256, 256, 0, stream>>>(tv, tbl, T);
    // Kernel 1: coefficients
    k_coeffs<<<(N + 255) / 256, 256, 0, stream>>>(amp, ph, w, nbr, bmin, bmax, pq, N, K);
    // Kernel 2: sweep
    constexpr int ROWS = 25;
    const int nq = (T + 3) / 4;
    dim3 grid((N + ROWS - 1) / ROWS, (nq + 255) / 256);
    k_sweep<ROWS><<<grid, 256, 0, stream>>>(co, lt, pq, tbl, tv, out, N, T);
}